// Round 1
// baseline (130.533 us; speedup 1.0000x reference)
//
#include <hip/hip_runtime.h>
#include <hip/hip_bf16.h>

// ---------------- problem constants ----------------
// x: (16,128,64,64) f32; weight: (256,128,3,3) f32; bias: (256,) f32; P: (1,256,128,3,3) f32
// out: (16,256,64,64) f32
// KH_EFF=7, KW=3, PAD_H=3, PAD_W=1
#define NIMG 16
#define CIN 128
#define COUT 256
#define HH 64
#define WW 64
#define KHE 7
#define KW_ 3
#define HP (HH + 6)   // 70
#define WP (WW + 2)   // 66
#define KDIM (CIN * KHE * KW_)  // 2688

typedef __attribute__((ext_vector_type(8))) short short8;
typedef __attribute__((ext_vector_type(4))) float f32x4;

#define AS1(p) ((const __attribute__((address_space(1))) void*)(p))
#define AS3(p) ((__attribute__((address_space(3))) void*)(p))

// ---------------- kernel 1: pad + NCHW->NHWC transpose + f32->bf16 ----------------
// xp[n][hp][wp][i], hp = h+3, wp = w+1, zero borders
__global__ void __launch_bounds__(256) pad_convert(const float* __restrict__ x,
                                                   ushort* __restrict__ xp) {
  const int bid = blockIdx.x;          // 16*70
  const int n = bid / HP, hp = bid % HP;
  const int h = hp - 3;
  ushort* dst = xp + (size_t)(n * HP + hp) * (WP * CIN);
  const int tid = threadIdx.x;

  if (h < 0 || h >= HH) {
    // zero 66*128 bf16 = 16896 B = 1056 uint4
    uint4* p = (uint4*)dst;
    uint4 z; z.x = z.y = z.z = z.w = 0u;
    for (int idx = tid; idx < (WP * CIN * 2) / 16; idx += 256) p[idx] = z;
    return;
  }

  __shared__ ushort t[CIN][WW + 1];   // +1 pad to break bank conflict on transpose read
  // coalesced read of x[n][i][h][0..63]
  for (int it = 0; it < (CIN * WW) / 256; ++it) {
    int flat = it * 256 + tid;
    int i = flat >> 6, w = flat & 63;
    float v = x[(((size_t)n * CIN + i) * HH + h) * WW + w];
    __hip_bfloat16 b = __float2bfloat16(v);
    t[i][w] = *(ushort*)&b;
  }
  __syncthreads();
  // write xp row: (wp, i) with i fastest -> coalesced
  for (int it = 0; it < (WP * CIN) / 256; ++it) {
    int flat = it * 256 + tid;
    int wp = flat >> 7, i = flat & 127;
    int w = wp - 1;
    ushort v = (w < 0 || w >= WW) ? (ushort)0 : t[i][w];
    dst[flat] = v;
  }
}

// ---------------- kernel 2: build dense bf16 kernel ----------------
// kb[o][r][kw][i], r in [0,7): gather over 3 base taps with bilinear row interp
__global__ void __launch_bounds__(256) build_kb(const float* __restrict__ weight,
                                                const float* __restrict__ P,
                                                ushort* __restrict__ kb) {
  int idx = blockIdx.x * 256 + threadIdx.x;  // 256*3*128 = 98304 threads
  if (idx >= COUT * KW_ * CIN) return;
  int i = idx & 127;
  int kw = (idx >> 7) % 3;
  int o = idx / (KW_ * CIN);
  int base = (o * CIN + i) * 9 + kw;

  float a[KHE] = {0.f, 0.f, 0.f, 0.f, 0.f, 0.f, 0.f};
#pragma unroll
  for (int kh = 0; kh < 3; ++kh) {
    float wv = weight[base + kh * 3];
    float p = P[base + kh * 3];
    p = fminf(2.f, fmaxf(-2.f, p));
    float pos = (float)(kh + 2) + p;       // in [0,6]
    float fl = floorf(pos);
    float fr = pos - fl;
    int r0 = (int)fl;
    float c0 = wv * (1.f - fr);
    float c1 = wv * fr;
#pragma unroll
    for (int r = 0; r < KHE; ++r) {
      a[r] += ((r0 == r) ? c0 : 0.f) + ((r0 + 1 == r) ? c1 : 0.f);
    }
  }
#pragma unroll
  for (int r = 0; r < KHE; ++r) {
    __hip_bfloat16 b = __float2bfloat16(a[r]);
    kb[((size_t)(o * KHE + r) * KW_ + kw) * CIN + i] = *(ushort*)&b;
  }
}

// ---------------- kernel 3: implicit-GEMM conv via MFMA ----------------
// M = 65536 (n,h,w), N = 256 (o), K = 2688 (kh,kw,i)
// BM=BN=128, BK=64 (one (kh,kw,ichunk) per k-step, 42 steps), 4 waves
__global__ void __launch_bounds__(256) dcls_gemm(const ushort* __restrict__ xp,
                                                 const ushort* __restrict__ kb,
                                                 const float* __restrict__ bias,
                                                 float* __restrict__ out) {
  __shared__ __align__(16) ushort As[128 * 64];
  __shared__ __align__(16) ushort Bs[128 * 64];

  const int tid = threadIdx.x;
  const int lane = tid & 63;
  const int wv = tid >> 6;       // wave 0..3
  const int wm = wv >> 1;        // 2 waves along M
  const int wn = wv & 1;         // 2 waves along N

  const int bid = blockIdx.x;    // 1024 = 512 Mtiles * 2 Ntiles
  const int nt = bid & 1;
  const int mt = bid >> 1;
  const int m0 = mt << 7;
  const int o0 = nt << 7;

  // staging geometry: 8 lanes per LDS row, 16B per lane; source pre-swizzled
  const int lr = lane >> 3;      // row within 8-row issue block == (row&7)
  const int lc = lane & 7;       // 16B chunk
  const int swz8 = (lc ^ lr) * 8;  // element offset of swizzled chunk

  const ushort* pA[4];
  const ushort* pB[4];
#pragma unroll
  for (int j = 0; j < 4; ++j) {
    int r = wv * 32 + j * 8 + lr;         // LDS row (m or o within tile)
    int m = m0 + r;
    int ni = m >> 12, hh = (m >> 6) & 63, ww = m & 63;
    pA[j] = xp + (size_t)((ni * HP + hh) * WP + ww) * CIN + swz8;
    int o = o0 + r;
    pB[j] = kb + (size_t)o * KDIM + swz8;
  }

  f32x4 acc[4][4] = {};

  for (int s = 0; s < 42; ++s) {
    int kh = s / 6;
    int rem = s - kh * 6;
    int kw = rem >> 1;
    int ic = rem & 1;
    int offA = (kh * WP + kw) * CIN + ic * 64;   // elements
    int offB = (kh * KW_ + kw) * CIN + ic * 64;

#pragma unroll
    for (int j = 0; j < 4; ++j) {
      __builtin_amdgcn_global_load_lds(AS1(pA[j] + offA), AS3(&As[(wv * 32 + j * 8) * 64]), 16, 0, 0);
      __builtin_amdgcn_global_load_lds(AS1(pB[j] + offB), AS3(&Bs[(wv * 32 + j * 8) * 64]), 16, 0, 0);
    }
    __syncthreads();

    {
      const int g = lane >> 4, lm = lane & 15;
#pragma unroll
      for (int kk = 0; kk < 2; ++kk) {
        short8 af[4], bf[4];
#pragma unroll
        for (int f = 0; f < 4; ++f) {
          int rowA = wm * 64 + f * 16 + lm;
          int cbA = (kk * 64 + g * 16) ^ ((rowA & 7) << 4);
          af[f] = *(const short8*)((const char*)As + rowA * 128 + cbA);
          int rowB = wn * 64 + f * 16 + lm;
          int cbB = (kk * 64 + g * 16) ^ ((rowB & 7) << 4);
          bf[f] = *(const short8*)((const char*)Bs + rowB * 128 + cbB);
        }
#pragma unroll
        for (int fm = 0; fm < 4; ++fm)
#pragma unroll
          for (int fn = 0; fn < 4; ++fn)
            acc[fm][fn] = __builtin_amdgcn_mfma_f32_16x16x32_bf16(af[fm], bf[fn], acc[fm][fn], 0, 0, 0);
      }
    }
    __syncthreads();
  }

  // epilogue: C/D layout col=lane&15 (o), row=(lane>>4)*4+reg (m); fuse bias
  const int g = lane >> 4, lm = lane & 15;
#pragma unroll
  for (int fn = 0; fn < 4; ++fn) {
    int o = o0 + wn * 64 + fn * 16 + lm;
    float bv = bias[o];
#pragma unroll
    for (int fm = 0; fm < 4; ++fm) {
      int m = m0 + wm * 64 + fm * 16 + g * 4;   // 4 consecutive m (same h row, w%4==0)
      int ni = m >> 12, hh = (m >> 6) & 63, ww = m & 63;
      float* dst = out + (size_t)((ni * COUT + o) * HH + hh) * WW + ww;
      f32x4 v = acc[fm][fn];
      v[0] += bv; v[1] += bv; v[2] += bv; v[3] += bv;
      *(f32x4*)dst = v;
    }
  }
}

// ---------------- launcher ----------------
extern "C" void kernel_launch(void* const* d_in, const int* in_sizes, int n_in,
                              void* d_out, int out_size, void* d_ws, size_t ws_size,
                              hipStream_t stream) {
  const float* x = (const float*)d_in[0];
  const float* weight = (const float*)d_in[1];
  const float* bias = (const float*)d_in[2];
  const float* P = (const float*)d_in[3];
  float* out = (float*)d_out;

  const size_t xp_elems = (size_t)NIMG * HP * WP * CIN;       // 9,461,760 bf16
  ushort* xp = (ushort*)d_ws;
  ushort* kb = (ushort*)((char*)d_ws + xp_elems * 2);         // +18,923,520 B

  hipLaunchKernelGGL(pad_convert, dim3(NIMG * HP), dim3(256), 0, stream, x, xp);
  hipLaunchKernelGGL(build_kb, dim3((COUT * KW_ * CIN + 255) / 256), dim3(256), 0, stream,
                     weight, P, kb);
  hipLaunchKernelGGL(dcls_gemm, dim3(1024), dim3(256), 0, stream, xp, kb, bias, out);
}

// Round 2
// 102.416 us; speedup vs baseline: 1.2745x; 1.2745x over previous
//
#include <hip/hip_runtime.h>
#include <hip/hip_bf16.h>

// ---------------- problem constants ----------------
#define NIMG 16
#define CIN 128
#define COUT 256
#define HH 64
#define WW 64
#define KHE 7
#define KW_ 3
#define HP (HH + 6)   // 70
#define WP (WW + 2)   // 66
#define KDIM (CIN * KHE * KW_)  // 2688
#define NKT 42                  // K-tiles of 64

typedef __attribute__((ext_vector_type(8))) short short8;
typedef __attribute__((ext_vector_type(4))) float f32x4;

#define AS1(p) ((const __attribute__((address_space(1))) void*)(p))
#define AS3(p) ((__attribute__((address_space(3))) void*)(p))

// ---------------- kernel 1: pad + NCHW->NHWC transpose + f32->bf16 ----------------
__global__ void __launch_bounds__(256) pad_convert(const float* __restrict__ x,
                                                   ushort* __restrict__ xp) {
  const int bid = blockIdx.x;          // 16*70
  const int n = bid / HP, hp = bid % HP;
  const int h = hp - 3;
  ushort* dst = xp + (size_t)(n * HP + hp) * (WP * CIN);
  const int tid = threadIdx.x;

  if (h < 0 || h >= HH) {
    uint4* p = (uint4*)dst;
    uint4 z; z.x = z.y = z.z = z.w = 0u;
    for (int idx = tid; idx < (WP * CIN * 2) / 16; idx += 256) p[idx] = z;
    return;
  }

  __shared__ ushort t[CIN][WW + 1];
  for (int it = 0; it < (CIN * WW) / 256; ++it) {
    int flat = it * 256 + tid;
    int i = flat >> 6, w = flat & 63;
    float v = x[(((size_t)n * CIN + i) * HH + h) * WW + w];
    __hip_bfloat16 b = __float2bfloat16(v);
    t[i][w] = *(ushort*)&b;
  }
  __syncthreads();
  for (int it = 0; it < (WP * CIN) / 256; ++it) {
    int flat = it * 256 + tid;
    int wp = flat >> 7, i = flat & 127;
    int w = wp - 1;
    ushort v = (w < 0 || w >= WW) ? (ushort)0 : t[i][w];
    dst[flat] = v;
  }
}

// ---------------- kernel 2: build dense bf16 kernel ----------------
__global__ void __launch_bounds__(256) build_kb(const float* __restrict__ weight,
                                                const float* __restrict__ P,
                                                ushort* __restrict__ kb) {
  int idx = blockIdx.x * 256 + threadIdx.x;
  if (idx >= COUT * KW_ * CIN) return;
  int i = idx & 127;
  int kw = (idx >> 7) % 3;
  int o = idx / (KW_ * CIN);
  int base = (o * CIN + i) * 9 + kw;

  float a[KHE] = {0.f, 0.f, 0.f, 0.f, 0.f, 0.f, 0.f};
#pragma unroll
  for (int kh = 0; kh < 3; ++kh) {
    float wv = weight[base + kh * 3];
    float p = P[base + kh * 3];
    p = fminf(2.f, fmaxf(-2.f, p));
    float pos = (float)(kh + 2) + p;
    float fl = floorf(pos);
    float fr = pos - fl;
    int r0 = (int)fl;
    float c0 = wv * (1.f - fr);
    float c1 = wv * fr;
#pragma unroll
    for (int r = 0; r < KHE; ++r) {
      a[r] += ((r0 == r) ? c0 : 0.f) + ((r0 + 1 == r) ? c1 : 0.f);
    }
  }
#pragma unroll
  for (int r = 0; r < KHE; ++r) {
    __hip_bfloat16 b = __float2bfloat16(a[r]);
    kb[((size_t)(o * KHE + r) * KW_ + kw) * CIN + i] = *(ushort*)&b;
  }
}

// ---------------- kernel 3: implicit-GEMM conv, 256x256 tile, counted-vmcnt pipeline ----------------
// M = 65536, N = 256 (one tile), K = 2688 = 42 x 64
// 8 waves (2M x 4N), per-wave output 128x64, acc = 32 x f32x4
__global__ void __launch_bounds__(512, 2) dcls_gemm(const ushort* __restrict__ xp,
                                                    const ushort* __restrict__ kb,
                                                    const float* __restrict__ bias,
                                                    float* __restrict__ out) {
  __shared__ __align__(16) ushort As[2][256 * 64];   // 64 KiB
  __shared__ __align__(16) ushort Bs[2][256 * 64];   // 64 KiB

  const int tid = threadIdx.x;
  const int lane = tid & 63;
  const int wv = tid >> 6;       // 0..7
  const int wr = wv >> 2;        // 0..1 along M
  const int wc = wv & 3;         // 0..3 along N
  const int g = lane >> 4;
  const int lm = lane & 15;
  const int m0 = blockIdx.x << 8;

  // staging: 512 threads x 16B = 8KB per load-instr = 64 rows of 64 elems
  const int srow = tid >> 3;                       // row within 64-row block
  const int swz = ((tid & 7) ^ (srow & 7)) * 8;    // pre-swizzled source chunk (rule #21)

  const ushort* pA[4];
  const ushort* pB[4];
#pragma unroll
  for (int j = 0; j < 4; ++j) {
    int r = j * 64 + srow;
    int m = m0 + r;
    int ni = m >> 12, hh = (m >> 6) & 63, ww = m & 63;
    pA[j] = xp + (size_t)((ni * HP + hh) * WP + ww) * CIN + swz;
    pB[j] = kb + (size_t)r * KDIM + swz;           // o = r (single N tile)
  }

#define STAGE(c, kt) do { \
    int kh_ = (kt) / 6; int rem_ = (kt) - kh_ * 6; \
    int kw2_ = rem_ >> 1; int ic_ = rem_ & 1; \
    int offA_ = (kh_ * WP + kw2_) * CIN + ic_ * 64; \
    int offB_ = (kh_ * KW_ + kw2_) * CIN + ic_ * 64; \
    _Pragma("unroll") \
    for (int j_ = 0; j_ < 4; ++j_) \
      __builtin_amdgcn_global_load_lds(AS1(pA[j_] + offA_), AS3(&As[c][(j_ * 64 + wv * 8) * 64]), 16, 0, 0); \
    _Pragma("unroll") \
    for (int j_ = 0; j_ < 4; ++j_) \
      __builtin_amdgcn_global_load_lds(AS1(pB[j_] + offB_), AS3(&Bs[c][(j_ * 64 + wv * 8) * 64]), 16, 0, 0); \
  } while (0)

  f32x4 acc[8][4] = {};
  const int swzR = (lm & 7) << 4;   // fragment-read swizzle (row&7 == lm&7 here)

  STAGE(0, 0);          // 8 loads/thread
  STAGE(1, 1);          // 16 outstanding

  for (int kt = 0; kt < NKT; ++kt) {
    const int c = kt & 1;
    // counted wait: tiles kt (oldest 8) must land; kt+1's 8 may stay in flight
    if (kt < NKT - 1) { asm volatile("s_waitcnt vmcnt(8)" ::: "memory"); }
    else              { asm volatile("s_waitcnt vmcnt(0)" ::: "memory"); }
    __builtin_amdgcn_s_barrier();          // all waves' kt loads landed
    __builtin_amdgcn_sched_barrier(0);     // no ds_read hoists above barrier

    const char* Ab = (const char*)&As[c][0];
    const char* Bb = (const char*)&Bs[c][0];

    // B fragments for the whole K-tile (reused across both M halves)
    short8 bf[4][2];
#pragma unroll
    for (int n = 0; n < 4; ++n)
#pragma unroll
      for (int kk = 0; kk < 2; ++kk) {
        int rowB = wc * 64 + n * 16 + lm;
        bf[n][kk] = *(const short8*)(Bb + rowB * 128 + ((kk * 64 + g * 16) ^ swzR));
      }

#pragma unroll
    for (int half = 0; half < 2; ++half) {
      short8 af[4][2];
#pragma unroll
      for (int m4 = 0; m4 < 4; ++m4)
#pragma unroll
        for (int kk = 0; kk < 2; ++kk) {
          int rowA = wr * 128 + half * 64 + m4 * 16 + lm;
          af[m4][kk] = *(const short8*)(Ab + rowA * 128 + ((kk * 64 + g * 16) ^ swzR));
        }
#pragma unroll
      for (int kk = 0; kk < 2; ++kk)
#pragma unroll
        for (int m4 = 0; m4 < 4; ++m4)
#pragma unroll
          for (int n = 0; n < 4; ++n)
            acc[half * 4 + m4][n] = __builtin_amdgcn_mfma_f32_16x16x32_bf16(
                af[m4][kk], bf[n][kk], acc[half * 4 + m4][n], 0, 0, 0);
    }

    __builtin_amdgcn_s_barrier();          // all waves done READING buf[c]
    __builtin_amdgcn_sched_barrier(0);     // stage must not hoist above
    if (kt + 2 < NKT) STAGE(c, kt + 2);    // refill freed buffer, 1 full iter ahead
  }
#undef STAGE

  // epilogue: C/D layout col(o)=lane&15, row(m)=(lane>>4)*4+reg; fuse bias
#pragma unroll
  for (int fn = 0; fn < 4; ++fn) {
    int o = wc * 64 + fn * 16 + lm;
    float bv = bias[o];
#pragma unroll
    for (int fm = 0; fm < 8; ++fm) {
      int m = m0 + wr * 128 + fm * 16 + g * 4;
      int ni = m >> 12, hh = (m >> 6) & 63, ww = m & 63;
      f32x4 v = acc[fm][fn];
      v[0] += bv; v[1] += bv; v[2] += bv; v[3] += bv;
      *(f32x4*)(out + (size_t)((ni * COUT + o) * HH + hh) * WW + ww) = v;
    }
  }
}

// ---------------- launcher ----------------
extern "C" void kernel_launch(void* const* d_in, const int* in_sizes, int n_in,
                              void* d_out, int out_size, void* d_ws, size_t ws_size,
                              hipStream_t stream) {
  const float* x = (const float*)d_in[0];
  const float* weight = (const float*)d_in[1];
  const float* bias = (const float*)d_in[2];
  const float* P = (const float*)d_in[3];
  float* out = (float*)d_out;

  const size_t xp_elems = (size_t)NIMG * HP * WP * CIN;
  ushort* xp = (ushort*)d_ws;
  ushort* kb = (ushort*)((char*)d_ws + xp_elems * 2);

  hipLaunchKernelGGL(pad_convert, dim3(NIMG * HP), dim3(256), 0, stream, x, xp);
  hipLaunchKernelGGL(build_kb, dim3((COUT * KW_ * CIN + 255) / 256), dim3(256), 0, stream,
                     weight, P, kb);
  hipLaunchKernelGGL(dcls_gemm, dim3(65536 / 256), dim3(512), 0, stream, xp, kb, bias, out);
}